// Round 1
// baseline (294.243 us; speedup 1.0000x reference)
//
#include <hip/hip_runtime.h>

#define NPOS (254*254)   // 64516
#define KTOP 128

// ---------------- workspace layout (floats) ----------------
#define OFF_X    0                          // 64*256*256 = 4194304
#define OFF_C    4194304                    // NPOS*32 = 2064512
#define OFF_MAXV 6258816                    // NPOS -> pad 64520
#define OFF_W1T  6323336                    // 192*64 = 12288
#define OFF_W2T  6335624                    // 576*32 = 18432
#define OFF_POS  6354056                    // 128 ints
#define OFF_REG  6354184                    // 128*576 = 73728
#define OFF_S    6427912                    // 576
#define OFF_ACC  6428488                    // 2048
// total 6430536 floats = 25.8 MB

// ---------------- weight transposes ----------------
__global__ __launch_bounds__(256) void kt_kernel(const float* __restrict__ fw,
                                                 const float* __restrict__ cw,
                                                 float* __restrict__ w1t,
                                                 float* __restrict__ w2t) {
    int t = blockIdx.x * 256 + threadIdx.x;
    if (t < 64 * 192) {                 // feat_w (64,192) -> w1t[k][oc]
        int oc = t / 192, k = t % 192;
        w1t[k * 64 + oc] = fw[t];
    }
    if (t < 32 * 576) {                 // cls_w (32,576) -> w2t[k][oc]
        int oc = t / 576, k = t % 576;
        w2t[k * 32 + oc] = cw[t];
    }
}

// ---------------- conv1: stride8/ks8 patches, relu ----------------
// block: 256 threads = 64 positions x 4 channel-groups(16 ch). grid: 256 rows * 4 = 1024
__global__ __launch_bounds__(256) void conv1_kernel(const float* __restrict__ x1,
                                                    const float* __restrict__ w1t,
                                                    const float* __restrict__ fb,
                                                    float* __restrict__ X) {
    __shared__ float plds[192 * 64];     // [k][pos] 48 KB
    const int b = blockIdx.x;
    const int r = b >> 2;
    const int cblk = (b & 3) * 64;       // starting output column
    const int tid = threadIdx.x;

    // stage input: 24 rows (ch,i) x 512 contiguous floats
    for (int q = tid; q < 3072; q += 256) {
        int seg = q >> 7;                // ch*8 + i
        int m = q & 127;                 // float4 index in the 512-float row
        int ch = seg >> 3, i = seg & 7;
        const float4 v = *reinterpret_cast<const float4*>(
            x1 + (size_t)ch * 2048 * 2048 + (size_t)(r * 8 + i) * 2048 + cblk * 8 + m * 4);
        int pos = m >> 1;
        int kbase = seg * 8 + (m & 1) * 4;
        plds[(kbase + 0) * 64 + pos] = v.x;
        plds[(kbase + 1) * 64 + pos] = v.y;
        plds[(kbase + 2) * 64 + pos] = v.z;
        plds[(kbase + 3) * 64 + pos] = v.w;
    }
    __syncthreads();

    const int pos = tid & 63;
    const int g = __builtin_amdgcn_readfirstlane(tid >> 6);   // wave-uniform group
    float acc[16];
#pragma unroll
    for (int cc = 0; cc < 16; ++cc) acc[cc] = 0.f;

    for (int k = 0; k < 192; ++k) {
        float p = plds[k * 64 + pos];
        const float* __restrict__ wr = w1t + k * 64 + g * 16;  // wave-uniform -> s_load
#pragma unroll
        for (int cc = 0; cc < 16; ++cc) acc[cc] += p * wr[cc];
    }
    float* xo = X + (size_t)(r * 256 + cblk + pos) * 64 + g * 16;
#pragma unroll
    for (int cc = 0; cc < 16; ++cc) {
        float v = acc[cc] + fb[g * 16 + cc];
        xo[cc] = v > 0.f ? v : 0.f;
    }
}

// ---------------- conv2: 3x3, K-split over input-channel halves ----------------
// block: 256 = 128 positions x 2 halves. grid: ceil(64516/128)=505
__global__ __launch_bounds__(256) void conv2_kernel(const float* __restrict__ X,
                                                    const float* __restrict__ w2t,
                                                    const float* __restrict__ cb,
                                                    float* __restrict__ cfull,
                                                    float* __restrict__ maxv) {
    __shared__ float lred[128 * 33];
    const int tid = threadIdx.x;
    const int pl = tid & 127;
    const int half = tid >> 7;
    const int p = blockIdx.x * 128 + pl;
    const bool valid = p < NPOS;
    const int r = valid ? p / 254 : 0;
    const int c = valid ? p % 254 : 0;

    float acc[32];
#pragma unroll
    for (int o = 0; o < 32; ++o) acc[o] = 0.f;

    if (valid) {
        const int chbase = half * 32;
        for (int di = 0; di < 3; ++di)
            for (int dj = 0; dj < 3; ++dj) {
                const float* __restrict__ xp =
                    X + (size_t)((r + di) * 256 + (c + dj)) * 64 + chbase;
#pragma unroll
                for (int ch4 = 0; ch4 < 8; ++ch4) {
                    float4 xv = *reinterpret_cast<const float4*>(xp + ch4 * 4);
                    float xs4[4] = {xv.x, xv.y, xv.z, xv.w};
#pragma unroll
                    for (int l = 0; l < 4; ++l) {
                        int ch = chbase + ch4 * 4 + l;
                        const float* __restrict__ wr = w2t + (ch * 9 + di * 3 + dj) * 32;
                        float xs = xs4[l];
#pragma unroll
                        for (int o = 0; o < 32; ++o) acc[o] += xs * wr[o];
                    }
                }
            }
    }
    if (half == 1) {
#pragma unroll
        for (int o = 0; o < 32; ++o) lred[pl * 33 + o] = acc[o];
    }
    __syncthreads();
    if (half == 0 && valid) {
        float m = -1e30f;
        float* co = cfull + (size_t)p * 32;
#pragma unroll
        for (int o = 0; o < 32; ++o) {
            float v = acc[o] + lred[pl * 33 + o] + cb[o];
            co[o] = v;
            m = fmaxf(m, v);
        }
        maxv[p] = m;
    }
}

// ---------------- exact top-128 (radix-bin + bitonic), single block ----------------
__global__ __launch_bounds__(1024) void topk_kernel(const float* __restrict__ maxv,
                                                    int* __restrict__ pos_out) {
    __shared__ unsigned int hist[4096];
    __shared__ unsigned int scnt[64];
    __shared__ unsigned int sBin, sCnt;
    __shared__ unsigned long long list[2048];
    const int tid = threadIdx.x;

    for (int i = tid; i < 4096; i += 1024) hist[i] = 0;
    __syncthreads();
    for (int i = tid; i < NPOS; i += 1024) {
        unsigned int u = __float_as_uint(maxv[i]);
        u = (u & 0x80000000u) ? ~u : (u | 0x80000000u);
        atomicAdd(&hist[u >> 20], 1u);
    }
    __syncthreads();
    if (tid < 64) {
        unsigned int s = 0;
        for (int j = 0; j < 64; ++j) s += hist[tid * 64 + j];
        scnt[tid] = s;
    }
    __syncthreads();
    if (tid == 0) {
        unsigned int cum = 0;
        int sb = 63;
        for (; sb > 0; --sb) {
            if (cum + scnt[sb] >= (unsigned)KTOP) break;
            cum += scnt[sb];
        }
        int bfound = sb * 64;
        for (int j = 63; j >= 0; --j) {
            unsigned int h = hist[sb * 64 + j];
            if (cum + h >= (unsigned)KTOP) { bfound = sb * 64 + j; break; }
            cum += h;
        }
        sBin = (unsigned)bfound;
        sCnt = 0;
    }
    __syncthreads();
    const unsigned int binb = sBin;
    for (int i = tid; i < NPOS; i += 1024) {
        unsigned int u = __float_as_uint(maxv[i]);
        u = (u & 0x80000000u) ? ~u : (u | 0x80000000u);
        if ((u >> 20) >= binb) {
            unsigned int slot = atomicAdd(&sCnt, 1u);
            if (slot < 2048)
                list[slot] = ((unsigned long long)u << 32) | (unsigned int)(~(unsigned int)i);
        }
    }
    __syncthreads();
    const int cnt = (int)sCnt;
    for (int i = tid; i < 2048; i += 1024)
        if (i >= cnt) list[i] = 0ull;   // pad: sorts last
    __syncthreads();
    // bitonic sort, descending by key=(u<<32)|~idx  (tie -> smaller idx first)
    for (unsigned int size = 2; size <= 2048; size <<= 1) {
        for (unsigned int stride = size >> 1; stride > 0; stride >>= 1) {
            __syncthreads();
            unsigned int i = tid;
            unsigned int ppos = ((i & ~(stride - 1)) << 1) | (i & (stride - 1));
            unsigned int partner = ppos + stride;
            unsigned long long a = list[ppos], bb = list[partner];
            bool descSeg = ((ppos & size) == 0);
            bool doswap = descSeg ? (a < bb) : (a > bb);
            if (doswap) { list[ppos] = bb; list[partner] = a; }
        }
    }
    __syncthreads();
    if (tid < KTOP) {
        unsigned long long kk = list[tid];
        pos_out[tid] = (int)(~(unsigned int)(kk & 0xFFFFFFFFull));
    }
}

// ---------------- cls_out gather ----------------
__global__ __launch_bounds__(256) void clsgather_kernel(const float* __restrict__ cfull,
                                                        const int* __restrict__ pos,
                                                        float* __restrict__ out) {
    int g = blockIdx.x * 256 + threadIdx.x;
    if (g >= 32 * 128) return;
    int k = g & 127, oc = g >> 7;
    out[2048 + oc * 128 + k] = cfull[(size_t)pos[k] * 32 + oc];
}

// ---------------- per-row l2norm of gathered patches ----------------
__global__ __launch_bounds__(64) void norm_kernel(const float* __restrict__ X,
                                                  const int* __restrict__ pos,
                                                  float* __restrict__ regn) {
    const int k = blockIdx.x;
    const int ch = threadIdx.x;
    const int p = pos[k];
    const int r0 = p / 254, c0 = p % 254;
    float v[9];
    float ss = 0.f;
#pragma unroll
    for (int fi = 0; fi < 3; ++fi)
#pragma unroll
        for (int fj = 0; fj < 3; ++fj) {
            float t = X[(size_t)((r0 + fi) * 256 + (c0 + fj)) * 64 + ch];
            v[fi * 3 + fj] = t;
            ss += t * t;
        }
#pragma unroll
    for (int o = 1; o < 64; o <<= 1) ss += __shfl_xor(ss, o);
    float scale = 1.0f / fmaxf(sqrtf(ss), 1e-12f);
#pragma unroll
    for (int q = 0; q < 9; ++q)
        regn[(size_t)k * 576 + ch * 9 + q] = v[q] * scale;
}

// ---------------- column sum + 128*shift ----------------
__global__ __launch_bounds__(576) void colsum_kernel(const float* __restrict__ regn,
                                                     const float* __restrict__ shift,
                                                     float* __restrict__ S) {
    int j = threadIdx.x;
    if (j >= 576) return;
    float s = 128.0f * shift[j];
    for (int k = 0; k < 128; ++k) s += regn[k * 576 + j];
    S[j] = s;
}

// ---------------- matvec: acc = S @ W^T + 128*lin_b ----------------
__global__ __launch_bounds__(256) void matvec_kernel(const float* __restrict__ S,
                                                     const float* __restrict__ lw,
                                                     const float* __restrict__ lb,
                                                     float* __restrict__ accv) {
    int f = blockIdx.x * 256 + threadIdx.x;   // 0..2047
    const float* __restrict__ wr = lw + (size_t)f * 576;
    float s = 0.f;
    for (int j = 0; j < 576; j += 4) {
        float4 w4 = *reinterpret_cast<const float4*>(wr + j);
        s += S[j] * w4.x + S[j + 1] * w4.y + S[j + 2] * w4.z + S[j + 3] * w4.w;
    }
    accv[f] = s + 128.0f * lb[f];
}

// ---------------- final l2norm -> desc ----------------
__global__ __launch_bounds__(1024) void finalize_kernel(const float* __restrict__ accv,
                                                        float* __restrict__ out) {
    __shared__ float red[32];
    int tid = threadIdx.x;
    float a = accv[tid], b = accv[tid + 1024];
    float ss = a * a + b * b;
#pragma unroll
    for (int o = 1; o < 64; o <<= 1) ss += __shfl_xor(ss, o);
    if ((tid & 63) == 0) red[tid >> 6] = ss;
    __syncthreads();
    if (tid < 16) {
        float t = red[tid];
#pragma unroll
        for (int o = 1; o < 16; o <<= 1) t += __shfl_xor(t, o);
        if (tid == 0) red[0] = t;
    }
    __syncthreads();
    float scale = 1.0f / fmaxf(sqrtf(red[0]), 1e-12f);
    out[tid] = a * scale;
    out[tid + 1024] = b * scale;
}

extern "C" void kernel_launch(void* const* d_in, const int* in_sizes, int n_in,
                              void* d_out, int out_size, void* d_ws, size_t ws_size,
                              hipStream_t stream) {
    const float* x1    = (const float*)d_in[0];
    const float* fw    = (const float*)d_in[1];
    const float* fb    = (const float*)d_in[2];
    const float* cw    = (const float*)d_in[3];
    const float* cb    = (const float*)d_in[4];
    const float* shift = (const float*)d_in[5];
    const float* lw    = (const float*)d_in[6];
    const float* lb    = (const float*)d_in[7];
    float* out = (float*)d_out;
    float* ws  = (float*)d_ws;

    float* X    = ws + OFF_X;
    float* C    = ws + OFF_C;
    float* MAXV = ws + OFF_MAXV;
    float* W1T  = ws + OFF_W1T;
    float* W2T  = ws + OFF_W2T;
    int*   POS  = (int*)(ws + OFF_POS);
    float* REGN = ws + OFF_REG;
    float* S    = ws + OFF_S;
    float* ACC  = ws + OFF_ACC;

    kt_kernel<<<72, 256, 0, stream>>>(fw, cw, W1T, W2T);
    conv1_kernel<<<1024, 256, 0, stream>>>(x1, W1T, fb, X);
    conv2_kernel<<<505, 256, 0, stream>>>(X, W2T, cb, C, MAXV);
    topk_kernel<<<1, 1024, 0, stream>>>(MAXV, POS);
    clsgather_kernel<<<16, 256, 0, stream>>>(C, POS, out);
    norm_kernel<<<128, 64, 0, stream>>>(X, POS, REGN);
    colsum_kernel<<<1, 576, 0, stream>>>(REGN, shift, S);
    matvec_kernel<<<8, 256, 0, stream>>>(S, lw, lb, ACC);
    finalize_kernel<<<1, 1024, 0, stream>>>(ACC, out);
}

// Round 2
// 159.881 us; speedup vs baseline: 1.8404x; 1.8404x over previous
//
#include <hip/hip_runtime.h>

#define NPOS (254*254)   // 64516
#define NPOSP 64520      // padded plane stride for C
#define KTOP 128

// ---------------- workspace layout (floats) ----------------
#define OFF_X    0                          // 64 planes * 65536 = 4194304
#define OFF_C    4194304                    // 32 planes * NPOSP = 2064640
#define OFF_MAXV 6258944                    // 64520
#define OFF_W1T  6323464                    // 192*64 = 12288
#define OFF_W2R  6335752                    // 576*32 = 18432
#define OFF_POS  6354184                    // 128 ints
#define OFF_REG  6354312                    // 128*576 = 73728
#define OFF_S    6428040                    // 576
#define OFF_ACC  6428616                    // 2048
// total ~6430664 floats = 25.7 MB

// ---------------- weight transposes / rearrange ----------------
__global__ __launch_bounds__(256) void kt_kernel(const float* __restrict__ fw,
                                                 const float* __restrict__ cw,
                                                 float* __restrict__ w1t,
                                                 float* __restrict__ w2r) {
    int t = blockIdx.x * 256 + threadIdx.x;
    if (t < 64 * 192) {                 // feat_w (64,192) -> w1t[k][oc]
        int oc = t / 192, k = t % 192;
        w1t[k * 64 + oc] = fw[t];
    }
    if (t < 32 * 576) {                 // cls_w (oc,ch,di,dj) -> w2r[((ch*3+di)*4+w)*24 + dj*8 + oo]
        int rem = t % 24;
        int tmp = t / 24;
        int dj = rem >> 3, oo = rem & 7;
        int w = tmp & 3;
        int chdi = tmp >> 2;
        int di = chdi % 3, ch = chdi / 3;
        int oc = w * 8 + oo;
        w2r[t] = cw[((oc * 64 + ch) * 3 + di) * 3 + dj];
    }
}

// ---------------- conv1: stride8/ks8 patches, relu, planar output ----------------
// block: 256 threads = 64 positions x 4 channel-groups(16 ch). grid: 256 rows * 4
__global__ __launch_bounds__(256) void conv1_kernel(const float* __restrict__ x1,
                                                    const float* __restrict__ w1t,
                                                    const float* __restrict__ fb,
                                                    float* __restrict__ X) {
    __shared__ float plds[192 * 64];     // [k][pos] 48 KB
    const int b = blockIdx.x;
    const int r = b >> 2;
    const int cblk = (b & 3) * 64;       // starting output column
    const int tid = threadIdx.x;

    // stage input: 24 segments (ch,i) x 512 contiguous floats
    for (int q = tid; q < 3072; q += 256) {
        int seg = q >> 7;                // ch*8 + i
        int m = q & 127;                 // float4 index in the 512-float row
        int ch = seg >> 3, i = seg & 7;
        const float4 v = *reinterpret_cast<const float4*>(
            x1 + (size_t)ch * 2048 * 2048 + (size_t)(r * 8 + i) * 2048 + cblk * 8 + m * 4);
        int pos = m >> 1;
        int kbase = seg * 8 + (m & 1) * 4;
        plds[(kbase + 0) * 64 + pos] = v.x;
        plds[(kbase + 1) * 64 + pos] = v.y;
        plds[(kbase + 2) * 64 + pos] = v.z;
        plds[(kbase + 3) * 64 + pos] = v.w;
    }
    __syncthreads();

    const int pos = tid & 63;
    const int g = __builtin_amdgcn_readfirstlane(tid >> 6);   // wave-uniform group
    float acc[16];
#pragma unroll
    for (int cc = 0; cc < 16; ++cc) acc[cc] = 0.f;

    for (int k = 0; k < 192; ++k) {
        float p = plds[k * 64 + pos];
        const float* __restrict__ wr = w1t + k * 64 + g * 16;  // wave-uniform -> s_load
#pragma unroll
        for (int cc = 0; cc < 16; ++cc) acc[cc] += p * wr[cc];
    }
    const int gpos = r * 256 + cblk + pos;
#pragma unroll
    for (int cc = 0; cc < 16; ++cc) {
        float v = acc[cc] + fb[g * 16 + cc];
        X[(size_t)(g * 16 + cc) * 65536 + gpos] = v > 0.f ? v : 0.f;
    }
}

// ---------------- conv2: 3x3 over planar X, coalesced ----------------
// block: 256 = 64 cols x 4 oc-groups(8 out each). grid: (4 col-groups, 254 rows)
__global__ __launch_bounds__(256) void conv2_kernel(const float* __restrict__ X,
                                                    const float* __restrict__ w2r,
                                                    const float* __restrict__ cb,
                                                    float* __restrict__ C,
                                                    float* __restrict__ maxv) {
    __shared__ float lmax[4][64];
    const int lane = threadIdx.x & 63;
    const int w = __builtin_amdgcn_readfirstlane(threadIdx.x >> 6);
    const int r = blockIdx.y;
    const int c = blockIdx.x * 64 + lane;
    const bool valid = c < 254;

    float acc[8];
#pragma unroll
    for (int o = 0; o < 8; ++o) acc[o] = 0.f;

    const float* __restrict__ xb = X + r * 256 + c;
    for (int ch = 0; ch < 64; ++ch) {
        const float* __restrict__ xp = xb + (size_t)ch * 65536;
#pragma unroll
        for (int di = 0; di < 3; ++di) {
            float x0 = xp[di * 256 + 0];
            float x1 = xp[di * 256 + 1];
            float x2 = xp[di * 256 + 2];
            const float* __restrict__ wr = w2r + ((ch * 3 + di) * 4 + w) * 24;
#pragma unroll
            for (int o = 0; o < 8; ++o)
                acc[o] += x0 * wr[o] + x1 * wr[8 + o] + x2 * wr[16 + o];
        }
    }

    float pm = -1e30f;
    const int p = r * 254 + c;
    if (valid) {
#pragma unroll
        for (int o = 0; o < 8; ++o) {
            float v = acc[o] + cb[w * 8 + o];
            C[(size_t)(w * 8 + o) * NPOSP + p] = v;
            pm = fmaxf(pm, v);
        }
    }
    lmax[w][lane] = pm;
    __syncthreads();
    if (w == 0 && valid) {
        float m = fmaxf(fmaxf(lmax[0][lane], lmax[1][lane]),
                        fmaxf(lmax[2][lane], lmax[3][lane]));
        maxv[p] = m;
    }
}

// ---------------- exact top-128 (radix-bin + rank selection), single block ----------------
__global__ __launch_bounds__(1024) void topk_kernel(const float* __restrict__ maxv,
                                                    int* __restrict__ pos_out) {
    __shared__ unsigned int hist[4096];
    __shared__ unsigned int scnt[64];
    __shared__ unsigned int sBin, sCnt;
    __shared__ unsigned long long list[2048];
    const int tid = threadIdx.x;

    for (int i = tid; i < 4096; i += 1024) hist[i] = 0;
    __syncthreads();
    for (int i = tid; i < NPOS; i += 1024) {
        unsigned int u = __float_as_uint(maxv[i]);
        u = (u & 0x80000000u) ? ~u : (u | 0x80000000u);
        atomicAdd(&hist[u >> 20], 1u);
    }
    __syncthreads();
    if (tid < 64) {
        unsigned int s = 0;
        for (int j = 0; j < 64; ++j) s += hist[tid * 64 + j];
        scnt[tid] = s;
    }
    __syncthreads();
    if (tid == 0) {
        unsigned int cum = 0;
        int sb = 63;
        for (; sb > 0; --sb) {
            if (cum + scnt[sb] >= (unsigned)KTOP) break;
            cum += scnt[sb];
        }
        int bfound = sb * 64;
        for (int j = 63; j >= 0; --j) {
            unsigned int h = hist[sb * 64 + j];
            if (cum + h >= (unsigned)KTOP) { bfound = sb * 64 + j; break; }
            cum += h;
        }
        sBin = (unsigned)bfound;
        sCnt = 0;
    }
    __syncthreads();
    const unsigned int binb = sBin;
    for (int i = tid; i < NPOS; i += 1024) {
        unsigned int u = __float_as_uint(maxv[i]);
        u = (u & 0x80000000u) ? ~u : (u | 0x80000000u);
        if ((u >> 20) >= binb) {
            unsigned int slot = atomicAdd(&sCnt, 1u);
            if (slot < 2048)
                list[slot] = ((unsigned long long)u << 32) | (unsigned int)(~(unsigned int)i);
        }
    }
    __syncthreads();
    const int cnt = (int)(sCnt < 2048u ? sCnt : 2048u);
    // rank selection: rank_i = #{ j : key_j > key_i }; keys unique (idx in low bits)
    for (int i = tid; i < cnt; i += 1024) {
        unsigned long long ki = list[i];
        int rank = 0;
        for (int j = 0; j < cnt; ++j) rank += (list[j] > ki) ? 1 : 0;
        if (rank < KTOP)
            pos_out[rank] = (int)(~(unsigned int)(ki & 0xFFFFFFFFull));
    }
}

// ---------------- cls_out gather (planar C) ----------------
__global__ __launch_bounds__(256) void clsgather_kernel(const float* __restrict__ C,
                                                        const int* __restrict__ pos,
                                                        float* __restrict__ out) {
    int g = blockIdx.x * 256 + threadIdx.x;
    if (g >= 32 * 128) return;
    int k = g & 127, oc = g >> 7;
    out[2048 + oc * 128 + k] = C[(size_t)oc * NPOSP + pos[k]];
}

// ---------------- per-row l2norm of gathered patches (planar X) ----------------
__global__ __launch_bounds__(64) void norm_kernel(const float* __restrict__ X,
                                                  const int* __restrict__ pos,
                                                  float* __restrict__ regn) {
    const int k = blockIdx.x;
    const int ch = threadIdx.x;
    const int p = pos[k];
    const int r0 = p / 254, c0 = p % 254;
    float v[9];
    float ss = 0.f;
#pragma unroll
    for (int fi = 0; fi < 3; ++fi)
#pragma unroll
        for (int fj = 0; fj < 3; ++fj) {
            float t = X[(size_t)ch * 65536 + (r0 + fi) * 256 + (c0 + fj)];
            v[fi * 3 + fj] = t;
            ss += t * t;
        }
#pragma unroll
    for (int o = 1; o < 64; o <<= 1) ss += __shfl_xor(ss, o);
    float scale = 1.0f / fmaxf(sqrtf(ss), 1e-12f);
#pragma unroll
    for (int q = 0; q < 9; ++q)
        regn[(size_t)k * 576 + ch * 9 + q] = v[q] * scale;
}

// ---------------- column sum + 128*shift ----------------
__global__ __launch_bounds__(576) void colsum_kernel(const float* __restrict__ regn,
                                                     const float* __restrict__ shift,
                                                     float* __restrict__ S) {
    int j = threadIdx.x;
    if (j >= 576) return;
    float s = 128.0f * shift[j];
    for (int k = 0; k < 128; ++k) s += regn[k * 576 + j];
    S[j] = s;
}

// ---------------- matvec: acc = S @ W^T + 128*lin_b ----------------
__global__ __launch_bounds__(256) void matvec_kernel(const float* __restrict__ S,
                                                     const float* __restrict__ lw,
                                                     const float* __restrict__ lb,
                                                     float* __restrict__ accv) {
    int f = blockIdx.x * 256 + threadIdx.x;   // 0..2047
    const float* __restrict__ wr = lw + (size_t)f * 576;
    float s = 0.f;
    for (int j = 0; j < 576; j += 4) {
        float4 w4 = *reinterpret_cast<const float4*>(wr + j);
        s += S[j] * w4.x + S[j + 1] * w4.y + S[j + 2] * w4.z + S[j + 3] * w4.w;
    }
    accv[f] = s + 128.0f * lb[f];
}

// ---------------- final l2norm -> desc ----------------
__global__ __launch_bounds__(1024) void finalize_kernel(const float* __restrict__ accv,
                                                        float* __restrict__ out) {
    __shared__ float red[32];
    int tid = threadIdx.x;
    float a = accv[tid], b = accv[tid + 1024];
    float ss = a * a + b * b;
#pragma unroll
    for (int o = 1; o < 64; o <<= 1) ss += __shfl_xor(ss, o);
    if ((tid & 63) == 0) red[tid >> 6] = ss;
    __syncthreads();
    if (tid < 16) {
        float t = red[tid];
#pragma unroll
        for (int o = 1; o < 16; o <<= 1) t += __shfl_xor(t, o);
        if (tid == 0) red[0] = t;
    }
    __syncthreads();
    float scale = 1.0f / fmaxf(sqrtf(red[0]), 1e-12f);
    out[tid] = a * scale;
    out[tid + 1024] = b * scale;
}

extern "C" void kernel_launch(void* const* d_in, const int* in_sizes, int n_in,
                              void* d_out, int out_size, void* d_ws, size_t ws_size,
                              hipStream_t stream) {
    const float* x1    = (const float*)d_in[0];
    const float* fw    = (const float*)d_in[1];
    const float* fb    = (const float*)d_in[2];
    const float* cw    = (const float*)d_in[3];
    const float* cb    = (const float*)d_in[4];
    const float* shift = (const float*)d_in[5];
    const float* lw    = (const float*)d_in[6];
    const float* lb    = (const float*)d_in[7];
    float* out = (float*)d_out;
    float* ws  = (float*)d_ws;

    float* X    = ws + OFF_X;
    float* C    = ws + OFF_C;
    float* MAXV = ws + OFF_MAXV;
    float* W1T  = ws + OFF_W1T;
    float* W2R  = ws + OFF_W2R;
    int*   POS  = (int*)(ws + OFF_POS);
    float* REGN = ws + OFF_REG;
    float* S    = ws + OFF_S;
    float* ACC  = ws + OFF_ACC;

    kt_kernel<<<72, 256, 0, stream>>>(fw, cw, W1T, W2R);
    conv1_kernel<<<1024, 256, 0, stream>>>(x1, W1T, fb, X);
    conv2_kernel<<<dim3(4, 254), 256, 0, stream>>>(X, W2R, cb, C, MAXV);
    topk_kernel<<<1, 1024, 0, stream>>>(MAXV, POS);
    clsgather_kernel<<<16, 256, 0, stream>>>(C, POS, out);
    norm_kernel<<<128, 64, 0, stream>>>(X, POS, REGN);
    colsum_kernel<<<1, 576, 0, stream>>>(REGN, shift, S);
    matvec_kernel<<<8, 256, 0, stream>>>(S, lw, lb, ACC);
    finalize_kernel<<<1, 1024, 0, stream>>>(ACC, out);
}

// Round 3
// 144.295 us; speedup vs baseline: 2.0392x; 1.1080x over previous
//
#include <hip/hip_runtime.h>

#define NPOS (254*254)   // 64516
#define NPOSP 64520      // padded plane stride for C / maxv
#define KTOP 128

// ---------------- workspace layout (floats) ----------------
#define OFF_X    0                          // 64 planes * 65536 = 4194304
#define OFF_C    4194304                    // 32 planes * NPOSP = 2064640
#define OFF_MAXV 6258944                    // 64520
#define OFF_W1T  6323464                    // 192*64 = 12288
#define OFF_W2R  6335752                    // 576*32 = 18432
#define OFF_POS  6354184                    // 128 ints
#define OFF_REG  6354312                    // 128*576 = 73728
#define OFF_S    6428040                    // 576
#define OFF_ACC  6428616                    // 2048

// ---------------- weight transposes / rearrange + maxv pad init ----------------
__global__ __launch_bounds__(256) void kt_kernel(const float* __restrict__ fw,
                                                 const float* __restrict__ cw,
                                                 float* __restrict__ w1t,
                                                 float* __restrict__ w2r,
                                                 float* __restrict__ maxv) {
    int t = blockIdx.x * 256 + threadIdx.x;
    if (t < 64 * 192) {                 // feat_w (64,192) -> w1t[k][oc]
        int oc = t / 192, k = t % 192;
        w1t[k * 64 + oc] = fw[t];
    }
    if (t < 32 * 576) {                 // cls_w (oc,ch,di,dj) -> w2r[((ch*3+di)*4+w)*24 + dj*8 + oo]
        int rem = t % 24;
        int tmp = t / 24;
        int dj = rem >> 3, oo = rem & 7;
        int w = tmp & 3;
        int chdi = tmp >> 2;
        int di = chdi % 3, ch = chdi / 3;
        int oc = w * 8 + oo;
        w2r[t] = cw[((oc * 64 + ch) * 3 + di) * 3 + dj];
    }
    if (t < (NPOSP - NPOS)) maxv[NPOS + t] = -1e30f;   // pad tail for float4 scans
}

// ---------------- conv1: stride8/ks8 patches, relu, planar output ----------------
// block: 256 threads = 64 positions x 4 channel-groups(16 ch). grid: 256 rows * 4
__global__ __launch_bounds__(256) void conv1_kernel(const float* __restrict__ x1,
                                                    const float* __restrict__ w1t,
                                                    const float* __restrict__ fb,
                                                    float* __restrict__ X) {
    __shared__ float plds[192 * 64];     // [k][pos] 48 KB
    const int b = blockIdx.x;
    const int r = b >> 2;
    const int cblk = (b & 3) * 64;       // starting output column
    const int tid = threadIdx.x;

    // stage input: 24 segments (ch,i) x 512 contiguous floats
    for (int q = tid; q < 3072; q += 256) {
        int seg = q >> 7;                // ch*8 + i
        int m = q & 127;                 // float4 index in the 512-float row
        int ch = seg >> 3, i = seg & 7;
        const float4 v = *reinterpret_cast<const float4*>(
            x1 + (size_t)ch * 2048 * 2048 + (size_t)(r * 8 + i) * 2048 + cblk * 8 + m * 4);
        int pos = m >> 1;
        int kbase = seg * 8 + (m & 1) * 4;
        plds[(kbase + 0) * 64 + pos] = v.x;
        plds[(kbase + 1) * 64 + pos] = v.y;
        plds[(kbase + 2) * 64 + pos] = v.z;
        plds[(kbase + 3) * 64 + pos] = v.w;
    }
    __syncthreads();

    const int pos = tid & 63;
    const int g = __builtin_amdgcn_readfirstlane(tid >> 6);   // wave-uniform group
    float acc[16];
#pragma unroll
    for (int cc = 0; cc < 16; ++cc) acc[cc] = 0.f;

    for (int k = 0; k < 192; ++k) {
        float p = plds[k * 64 + pos];
        const float* __restrict__ wr = w1t + k * 64 + g * 16;  // wave-uniform -> s_load
#pragma unroll
        for (int cc = 0; cc < 16; ++cc) acc[cc] += p * wr[cc];
    }
    const int gpos = r * 256 + cblk + pos;
#pragma unroll
    for (int cc = 0; cc < 16; ++cc) {
        float v = acc[cc] + fb[g * 16 + cc];
        X[(size_t)(g * 16 + cc) * 65536 + gpos] = v > 0.f ? v : 0.f;
    }
}

// ---------------- conv2: 3x3 over planar X, coalesced, deep ILP ----------------
// block: 256 = 64 cols x 4 oc-groups(8 out each). grid: (4 col-groups, 254 rows)
__global__ __launch_bounds__(256) void conv2_kernel(const float* __restrict__ X,
                                                    const float* __restrict__ w2r,
                                                    const float* __restrict__ cb,
                                                    float* __restrict__ C,
                                                    float* __restrict__ maxv) {
    __shared__ float lmax[4][64];
    const int lane = threadIdx.x & 63;
    const int w = __builtin_amdgcn_readfirstlane(threadIdx.x >> 6);
    const int r = blockIdx.y;
    const int c = blockIdx.x * 64 + lane;
    const bool valid = c < 254;

    float acc[8];
#pragma unroll
    for (int o = 0; o < 8; ++o) acc[o] = 0.f;

    const float* __restrict__ xb = X + r * 256 + c;
    const float* __restrict__ wb = w2r + w * 24;
#pragma unroll 4
    for (int ch = 0; ch < 64; ++ch) {
        const float* __restrict__ xp = xb + (size_t)ch * 65536;
        float xv[9];
#pragma unroll
        for (int di = 0; di < 3; ++di) {
            xv[di * 3 + 0] = xp[di * 256 + 0];
            xv[di * 3 + 1] = xp[di * 256 + 1];
            xv[di * 3 + 2] = xp[di * 256 + 2];
        }
        const float* __restrict__ wr = wb + ch * 288;
#pragma unroll
        for (int di = 0; di < 3; ++di) {
#pragma unroll
            for (int o = 0; o < 8; ++o)
                acc[o] += xv[di * 3 + 0] * wr[di * 96 + o]
                        + xv[di * 3 + 1] * wr[di * 96 + 8 + o]
                        + xv[di * 3 + 2] * wr[di * 96 + 16 + o];
        }
    }

    float pm = -1e30f;
    const int p = r * 254 + c;
    if (valid) {
#pragma unroll
        for (int o = 0; o < 8; ++o) {
            float v = acc[o] + cb[w * 8 + o];
            C[(size_t)(w * 8 + o) * NPOSP + p] = v;
            pm = fmaxf(pm, v);
        }
    }
    lmax[w][lane] = pm;
    __syncthreads();
    if (w == 0 && valid) {
        float m = fmaxf(fmaxf(lmax[0][lane], lmax[1][lane]),
                        fmaxf(lmax[2][lane], lmax[3][lane]));
        maxv[p] = m;
    }
}

// ---------------- exact top-128 (radix-bin + rank selection), single block ----------------
__global__ __launch_bounds__(1024) void topk_kernel(const float* __restrict__ maxv,
                                                    int* __restrict__ pos_out) {
    __shared__ unsigned int hist[4096];
    __shared__ unsigned int scnt[64];
    __shared__ unsigned int sBin, sCnt;
    __shared__ unsigned long long list[2048];
    const int tid = threadIdx.x;
    const float4* __restrict__ mv4 = reinterpret_cast<const float4*>(maxv);

    for (int i = tid; i < 4096; i += 1024) hist[i] = 0;
    __syncthreads();
    for (int i = tid; i < NPOSP / 4; i += 1024) {
        float4 v = mv4[i];
        float vs[4] = {v.x, v.y, v.z, v.w};
#pragma unroll
        for (int l = 0; l < 4; ++l) {
            unsigned int u = __float_as_uint(vs[l]);
            u = (u & 0x80000000u) ? ~u : (u | 0x80000000u);
            atomicAdd(&hist[u >> 20], 1u);
        }
    }
    __syncthreads();
    if (tid < 64) {
        unsigned int s = 0;
        for (int j = 0; j < 64; ++j) s += hist[tid * 64 + j];
        scnt[tid] = s;
    }
    __syncthreads();
    if (tid == 0) {
        unsigned int cum = 0;
        int sb = 63;
        for (; sb > 0; --sb) {
            if (cum + scnt[sb] >= (unsigned)KTOP) break;
            cum += scnt[sb];
        }
        int bfound = sb * 64;
        for (int j = 63; j >= 0; --j) {
            unsigned int h = hist[sb * 64 + j];
            if (cum + h >= (unsigned)KTOP) { bfound = sb * 64 + j; break; }
            cum += h;
        }
        sBin = (unsigned)bfound;
        sCnt = 0;
    }
    __syncthreads();
    const unsigned int binb = sBin;
    for (int i = tid; i < NPOSP / 4; i += 1024) {
        float4 v = mv4[i];
        float vs[4] = {v.x, v.y, v.z, v.w};
#pragma unroll
        for (int l = 0; l < 4; ++l) {
            unsigned int u = __float_as_uint(vs[l]);
            u = (u & 0x80000000u) ? ~u : (u | 0x80000000u);
            int idx = i * 4 + l;
            if ((u >> 20) >= binb && idx < NPOS) {
                unsigned int slot = atomicAdd(&sCnt, 1u);
                if (slot < 2048)
                    list[slot] = ((unsigned long long)u << 32) | (unsigned int)(~(unsigned int)idx);
            }
        }
    }
    __syncthreads();
    const int cnt = (int)(sCnt < 2048u ? sCnt : 2048u);
    // rank selection: rank_i = #{ j : key_j > key_i }; keys unique (idx in low bits)
    for (int i = tid; i < cnt; i += 1024) {
        unsigned long long ki = list[i];
        int rank = 0;
        for (int j = 0; j < cnt; ++j) rank += (list[j] > ki) ? 1 : 0;
        if (rank < KTOP)
            pos_out[rank] = (int)(~(unsigned int)(ki & 0xFFFFFFFFull));
    }
}

// ---------------- fused: per-row l2norm of patches + cls_out gather ----------------
// grid: 128 blocks (one per k), 64 threads
__global__ __launch_bounds__(64) void gather_kernel(const float* __restrict__ X,
                                                    const float* __restrict__ C,
                                                    const int* __restrict__ pos,
                                                    float* __restrict__ regn,
                                                    float* __restrict__ out) {
    const int k = blockIdx.x;
    const int ch = threadIdx.x;
    const int p = pos[k];
    // cls gather: lanes 0..31 fetch C[oc][p]
    if (ch < 32) out[2048 + ch * 128 + k] = C[(size_t)ch * NPOSP + p];

    const int r0 = p / 254, c0 = p % 254;
    float v[9];
    float ss = 0.f;
#pragma unroll
    for (int fi = 0; fi < 3; ++fi)
#pragma unroll
        for (int fj = 0; fj < 3; ++fj) {
            float t = X[(size_t)ch * 65536 + (r0 + fi) * 256 + (c0 + fj)];
            v[fi * 3 + fj] = t;
            ss += t * t;
        }
#pragma unroll
    for (int o = 1; o < 64; o <<= 1) ss += __shfl_xor(ss, o);
    float scale = 1.0f / fmaxf(sqrtf(ss), 1e-12f);
#pragma unroll
    for (int q = 0; q < 9; ++q)
        regn[(size_t)k * 576 + ch * 9 + q] = v[q] * scale;
}

// ---------------- column sum + 128*shift ----------------
__global__ __launch_bounds__(576) void colsum_kernel(const float* __restrict__ regn,
                                                     const float* __restrict__ shift,
                                                     float* __restrict__ S) {
    int j = threadIdx.x;
    if (j >= 576) return;
    float s = 128.0f * shift[j];
    for (int k = 0; k < 128; ++k) s += regn[k * 576 + j];
    S[j] = s;
}

// ---------------- matvec: acc = S @ W^T + 128*lin_b ----------------
__global__ __launch_bounds__(256) void matvec_kernel(const float* __restrict__ S,
                                                     const float* __restrict__ lw,
                                                     const float* __restrict__ lb,
                                                     float* __restrict__ accv) {
    int f = blockIdx.x * 256 + threadIdx.x;   // 0..2047
    const float* __restrict__ wr = lw + (size_t)f * 576;
    float s = 0.f;
    for (int j = 0; j < 576; j += 4) {
        float4 w4 = *reinterpret_cast<const float4*>(wr + j);
        s += S[j] * w4.x + S[j + 1] * w4.y + S[j + 2] * w4.z + S[j + 3] * w4.w;
    }
    accv[f] = s + 128.0f * lb[f];
}

// ---------------- final l2norm -> desc ----------------
__global__ __launch_bounds__(1024) void finalize_kernel(const float* __restrict__ accv,
                                                        float* __restrict__ out) {
    __shared__ float red[32];
    int tid = threadIdx.x;
    float a = accv[tid], b = accv[tid + 1024];
    float ss = a * a + b * b;
#pragma unroll
    for (int o = 1; o < 64; o <<= 1) ss += __shfl_xor(ss, o);
    if ((tid & 63) == 0) red[tid >> 6] = ss;
    __syncthreads();
    if (tid < 16) {
        float t = red[tid];
#pragma unroll
        for (int o = 1; o < 16; o <<= 1) t += __shfl_xor(t, o);
        if (tid == 0) red[0] = t;
    }
    __syncthreads();
    float scale = 1.0f / fmaxf(sqrtf(red[0]), 1e-12f);
    out[tid] = a * scale;
    out[tid + 1024] = b * scale;
}

extern "C" void kernel_launch(void* const* d_in, const int* in_sizes, int n_in,
                              void* d_out, int out_size, void* d_ws, size_t ws_size,
                              hipStream_t stream) {
    const float* x1    = (const float*)d_in[0];
    const float* fw    = (const float*)d_in[1];
    const float* fb    = (const float*)d_in[2];
    const float* cw    = (const float*)d_in[3];
    const float* cb    = (const float*)d_in[4];
    const float* shift = (const float*)d_in[5];
    const float* lw    = (const float*)d_in[6];
    const float* lb    = (const float*)d_in[7];
    float* out = (float*)d_out;
    float* ws  = (float*)d_ws;

    float* X    = ws + OFF_X;
    float* C    = ws + OFF_C;
    float* MAXV = ws + OFF_MAXV;
    float* W1T  = ws + OFF_W1T;
    float* W2R  = ws + OFF_W2R;
    int*   POS  = (int*)(ws + OFF_POS);
    float* REGN = ws + OFF_REG;
    float* S    = ws + OFF_S;
    float* ACC  = ws + OFF_ACC;

    kt_kernel<<<72, 256, 0, stream>>>(fw, cw, W1T, W2R, MAXV);
    conv1_kernel<<<1024, 256, 0, stream>>>(x1, W1T, fb, X);
    conv2_kernel<<<dim3(4, 254), 256, 0, stream>>>(X, W2R, cb, C, MAXV);
    topk_kernel<<<1, 1024, 0, stream>>>(MAXV, POS);
    gather_kernel<<<128, 64, 0, stream>>>(X, C, POS, REGN, out);
    colsum_kernel<<<1, 576, 0, stream>>>(REGN, shift, S);
    matvec_kernel<<<8, 256, 0, stream>>>(S, lw, lb, ACC);
    finalize_kernel<<<1, 1024, 0, stream>>>(ACC, out);
}

// Round 4
// 127.268 us; speedup vs baseline: 2.3120x; 1.1338x over previous
//
#include <hip/hip_runtime.h>

#define NPOS (254*254)   // 64516
#define NPOSP 64520      // padded plane stride for C / maxv
#define KTOP 128

// ---------------- workspace layout (floats) ----------------
#define OFF_X    0                          // 64 planes * 65536 = 4194304
#define OFF_C    4194304                    // 32 planes * NPOSP = 2064640
#define OFF_MAXV 6258944                    // 64520
#define OFF_W1T  6323464                    // 192*64 = 12288
#define OFF_W2R  6335752                    // 576*32 = 18432
#define OFF_POS  6354184                    // 128 ints
#define OFF_REG  6354312                    // 128*576 = 73728
#define OFF_S    6428040                    // 576
#define OFF_ACC  6428616                    // 2048

// ---------------- weight transposes / rearrange + maxv pad init ----------------
__global__ __launch_bounds__(256) void kt_kernel(const float* __restrict__ fw,
                                                 const float* __restrict__ cw,
                                                 float* __restrict__ w1t,
                                                 float* __restrict__ w2r,
                                                 float* __restrict__ maxv) {
    int t = blockIdx.x * 256 + threadIdx.x;
    if (t < 64 * 192) {                 // feat_w (64,192) -> w1t[k][oc]
        int oc = t / 192, k = t % 192;
        w1t[k * 64 + oc] = fw[t];
    }
    if (t < 32 * 576) {                 // cls_w (oc,ch,di,dj) -> w2r[((ch*3+di)*4+w)*24 + dj*8 + oo]
        int rem = t % 24;
        int tmp = t / 24;
        int dj = rem >> 3, oo = rem & 7;
        int w = tmp & 3;
        int chdi = tmp >> 2;
        int di = chdi % 3, ch = chdi / 3;
        int oc = w * 8 + oo;
        w2r[t] = cw[((oc * 64 + ch) * 3 + di) * 3 + dj];
    }
    if (t < (NPOSP - NPOS)) maxv[NPOS + t] = -1e30f;   // pad tail for float4 scans
}

// ---------------- conv1: stride8/ks8, no LDS, direct coalesced loads ----------------
// block: 256 = 64 cols x 4 ch-groups(16 ch). grid: (4 colgroups, 256 rows)
__global__ __launch_bounds__(256) void conv1_kernel(const float* __restrict__ x1,
                                                    const float* __restrict__ w1t,
                                                    const float* __restrict__ fb,
                                                    float* __restrict__ X) {
    const int lane = threadIdx.x & 63;
    const int g = __builtin_amdgcn_readfirstlane(threadIdx.x >> 6);  // wave-uniform
    const int r = blockIdx.y;
    const int c = blockIdx.x * 64 + lane;

    float acc[16];
#pragma unroll
    for (int cc = 0; cc < 16; ++cc) acc[cc] = 0.f;

    const float* __restrict__ xb = x1 + (size_t)r * 8 * 2048 + (size_t)c * 8;
    for (int seg = 0; seg < 24; ++seg) {       // seg = ic*8 + i
        const int ic = seg >> 3, i = seg & 7;
        const float* __restrict__ xr = xb + (size_t)ic * 2048 * 2048 + i * 2048;
        float4 a = *reinterpret_cast<const float4*>(xr);
        float4 b = *reinterpret_cast<const float4*>(xr + 4);
        float xs[8] = {a.x, a.y, a.z, a.w, b.x, b.y, b.z, b.w};
        const float* __restrict__ wseg = w1t + seg * 8 * 64 + g * 16;
#pragma unroll
        for (int j = 0; j < 8; ++j) {
            const float* __restrict__ wr = wseg + j * 64;   // wave-uniform -> s_load
            float xj = xs[j];
#pragma unroll
            for (int cc = 0; cc < 16; ++cc) acc[cc] += xj * wr[cc];
        }
    }
    const int gpos = r * 256 + c;
#pragma unroll
    for (int cc = 0; cc < 16; ++cc) {
        float v = acc[cc] + fb[g * 16 + cc];
        X[(size_t)(g * 16 + cc) * 65536 + gpos] = v > 0.f ? v : 0.f;
    }
}

// ---------------- conv2: 3x3 planar, 2-row register blocking ----------------
// block: 256 = 64 cols x 4 oc-groups(8 out each). grid: (4 colgroups, 127 row-pairs)
__global__ __launch_bounds__(256) void conv2_kernel(const float* __restrict__ X,
                                                    const float* __restrict__ w2r,
                                                    const float* __restrict__ cb,
                                                    float* __restrict__ C,
                                                    float* __restrict__ maxv) {
    __shared__ float lmax[4][2][64];
    const int lane = threadIdx.x & 63;
    const int w = __builtin_amdgcn_readfirstlane(threadIdx.x >> 6);
    const int r = blockIdx.y * 2;
    const int c = blockIdx.x * 64 + lane;
    const bool valid = c < 254;

    float acc[16];
#pragma unroll
    for (int o = 0; o < 16; ++o) acc[o] = 0.f;

    const float* __restrict__ xb = X + r * 256 + c;
    const float* __restrict__ wb = w2r + w * 24;
#pragma unroll 2
    for (int ch = 0; ch < 64; ++ch) {
        const float* __restrict__ xp = xb + (size_t)ch * 65536;
        float xv[12];
#pragma unroll
        for (int ri = 0; ri < 4; ++ri) {
            xv[ri * 3 + 0] = xp[ri * 256 + 0];
            xv[ri * 3 + 1] = xp[ri * 256 + 1];
            xv[ri * 3 + 2] = xp[ri * 256 + 2];
        }
        const float* __restrict__ wr = wb + ch * 288;
#pragma unroll
        for (int di = 0; di < 3; ++di) {
#pragma unroll
            for (int o = 0; o < 8; ++o) {
                float w0 = wr[di * 96 + o];
                float w1 = wr[di * 96 + 8 + o];
                float w2 = wr[di * 96 + 16 + o];
                acc[o]     += xv[di * 3 + 0] * w0 + xv[di * 3 + 1] * w1 + xv[di * 3 + 2] * w2;
                acc[8 + o] += xv[di * 3 + 3] * w0 + xv[di * 3 + 4] * w1 + xv[di * 3 + 5] * w2;
            }
        }
    }

    float pm0 = -1e30f, pm1 = -1e30f;
    const int p0 = r * 254 + c;
    if (valid) {
#pragma unroll
        for (int o = 0; o < 8; ++o) {
            float v0 = acc[o] + cb[w * 8 + o];
            float v1 = acc[8 + o] + cb[w * 8 + o];
            C[(size_t)(w * 8 + o) * NPOSP + p0] = v0;
            C[(size_t)(w * 8 + o) * NPOSP + p0 + 254] = v1;
            pm0 = fmaxf(pm0, v0);
            pm1 = fmaxf(pm1, v1);
        }
    }
    lmax[w][0][lane] = pm0;
    lmax[w][1][lane] = pm1;
    __syncthreads();
    if (w == 0 && valid) {
        float m0 = fmaxf(fmaxf(lmax[0][0][lane], lmax[1][0][lane]),
                         fmaxf(lmax[2][0][lane], lmax[3][0][lane]));
        float m1 = fmaxf(fmaxf(lmax[0][1][lane], lmax[1][1][lane]),
                         fmaxf(lmax[2][1][lane], lmax[3][1][lane]));
        maxv[p0] = m0;
        maxv[p0 + 254] = m1;
    }
}

// ---------------- exact top-128 (radix-bin + rank selection), single block ----------------
__global__ __launch_bounds__(1024) void topk_kernel(const float* __restrict__ maxv,
                                                    int* __restrict__ pos_out) {
    __shared__ unsigned int hist[4096];
    __shared__ unsigned int scnt[64];
    __shared__ unsigned int sBin, sCnt;
    __shared__ unsigned long long list[2048];
    const int tid = threadIdx.x;
    const float4* __restrict__ mv4 = reinterpret_cast<const float4*>(maxv);

    for (int i = tid; i < 4096; i += 1024) hist[i] = 0;
    __syncthreads();
    for (int i = tid; i < NPOSP / 4; i += 1024) {
        float4 v = mv4[i];
        float vs[4] = {v.x, v.y, v.z, v.w};
#pragma unroll
        for (int l = 0; l < 4; ++l) {
            unsigned int u = __float_as_uint(vs[l]);
            u = (u & 0x80000000u) ? ~u : (u | 0x80000000u);
            atomicAdd(&hist[u >> 20], 1u);
        }
    }
    __syncthreads();
    if (tid < 64) {
        unsigned int s = 0;
        for (int j = 0; j < 64; ++j) s += hist[tid * 64 + j];
        scnt[tid] = s;
    }
    __syncthreads();
    if (tid == 0) {
        unsigned int cum = 0;
        int sb = 63;
        for (; sb > 0; --sb) {
            if (cum + scnt[sb] >= (unsigned)KTOP) break;
            cum += scnt[sb];
        }
        int bfound = sb * 64;
        for (int j = 63; j >= 0; --j) {
            unsigned int h = hist[sb * 64 + j];
            if (cum + h >= (unsigned)KTOP) { bfound = sb * 64 + j; break; }
            cum += h;
        }
        sBin = (unsigned)bfound;
        sCnt = 0;
    }
    __syncthreads();
    const unsigned int binb = sBin;
    for (int i = tid; i < NPOSP / 4; i += 1024) {
        float4 v = mv4[i];
        float vs[4] = {v.x, v.y, v.z, v.w};
#pragma unroll
        for (int l = 0; l < 4; ++l) {
            unsigned int u = __float_as_uint(vs[l]);
            u = (u & 0x80000000u) ? ~u : (u | 0x80000000u);
            int idx = i * 4 + l;
            if ((u >> 20) >= binb && idx < NPOS) {
                unsigned int slot = atomicAdd(&sCnt, 1u);
                if (slot < 2048)
                    list[slot] = ((unsigned long long)u << 32) | (unsigned int)(~(unsigned int)idx);
            }
        }
    }
    __syncthreads();
    const int cnt = (int)(sCnt < 2048u ? sCnt : 2048u);
    // rank selection: rank_i = #{ j : key_j > key_i }; keys unique (idx in low bits)
    for (int i = tid; i < cnt; i += 1024) {
        unsigned long long ki = list[i];
        int rank = 0;
        for (int j = 0; j < cnt; ++j) rank += (list[j] > ki) ? 1 : 0;
        if (rank < KTOP)
            pos_out[rank] = (int)(~(unsigned int)(ki & 0xFFFFFFFFull));
    }
}

// ---------------- fused: per-row l2norm of patches + cls_out gather ----------------
// grid: 128 blocks (one per k), 64 threads
__global__ __launch_bounds__(64) void gather_kernel(const float* __restrict__ X,
                                                    const float* __restrict__ C,
                                                    const int* __restrict__ pos,
                                                    float* __restrict__ regn,
                                                    float* __restrict__ out) {
    const int k = blockIdx.x;
    const int ch = threadIdx.x;
    const int p = pos[k];
    // cls gather: lanes 0..31 fetch C[oc][p]
    if (ch < 32) out[2048 + ch * 128 + k] = C[(size_t)ch * NPOSP + p];

    const int r0 = p / 254, c0 = p % 254;
    float v[9];
    float ss = 0.f;
#pragma unroll
    for (int fi = 0; fi < 3; ++fi)
#pragma unroll
        for (int fj = 0; fj < 3; ++fj) {
            float t = X[(size_t)ch * 65536 + (r0 + fi) * 256 + (c0 + fj)];
            v[fi * 3 + fj] = t;
            ss += t * t;
        }
#pragma unroll
    for (int o = 1; o < 64; o <<= 1) ss += __shfl_xor(ss, o);
    float scale = 1.0f / fmaxf(sqrtf(ss), 1e-12f);
#pragma unroll
    for (int q = 0; q < 9; ++q)
        regn[(size_t)k * 576 + ch * 9 + q] = v[q] * scale;
}

// ---------------- column sum + 128*shift ----------------
__global__ __launch_bounds__(576) void colsum_kernel(const float* __restrict__ regn,
                                                     const float* __restrict__ shift,
                                                     float* __restrict__ S) {
    int j = threadIdx.x;
    if (j >= 576) return;
    float s = 128.0f * shift[j];
    for (int k = 0; k < 128; ++k) s += regn[k * 576 + j];
    S[j] = s;
}

// ---------------- matvec: acc = S @ W^T + 128*lin_b ----------------
__global__ __launch_bounds__(256) void matvec_kernel(const float* __restrict__ S,
                                                     const float* __restrict__ lw,
                                                     const float* __restrict__ lb,
                                                     float* __restrict__ accv) {
    int f = blockIdx.x * 256 + threadIdx.x;   // 0..2047
    const float* __restrict__ wr = lw + (size_t)f * 576;
    float s = 0.f;
    for (int j = 0; j < 576; j += 4) {
        float4 w4 = *reinterpret_cast<const float4*>(wr + j);
        s += S[j] * w4.x + S[j + 1] * w4.y + S[j + 2] * w4.z + S[j + 3] * w4.w;
    }
    accv[f] = s + 128.0f * lb[f];
}

// ---------------- final l2norm -> desc ----------------
__global__ __launch_bounds__(1024) void finalize_kernel(const float* __restrict__ accv,
                                                        float* __restrict__ out) {
    __shared__ float red[32];
    int tid = threadIdx.x;
    float a = accv[tid], b = accv[tid + 1024];
    float ss = a * a + b * b;
#pragma unroll
    for (int o = 1; o < 64; o <<= 1) ss += __shfl_xor(ss, o);
    if ((tid & 63) == 0) red[tid >> 6] = ss;
    __syncthreads();
    if (tid < 16) {
        float t = red[tid];
#pragma unroll
        for (int o = 1; o < 16; o <<= 1) t += __shfl_xor(t, o);
        if (tid == 0) red[0] = t;
    }
    __syncthreads();
    float scale = 1.0f / fmaxf(sqrtf(red[0]), 1e-12f);
    out[tid] = a * scale;
    out[tid + 1024] = b * scale;
}

extern "C" void kernel_launch(void* const* d_in, const int* in_sizes, int n_in,
                              void* d_out, int out_size, void* d_ws, size_t ws_size,
                              hipStream_t stream) {
    const float* x1    = (const float*)d_in[0];
    const float* fw    = (const float*)d_in[1];
    const float* fb    = (const float*)d_in[2];
    const float* cw    = (const float*)d_in[3];
    const float* cb    = (const float*)d_in[4];
    const float* shift = (const float*)d_in[5];
    const float* lw    = (const float*)d_in[6];
    const float* lb    = (const float*)d_in[7];
    float* out = (float*)d_out;
    float* ws  = (float*)d_ws;

    float* X    = ws + OFF_X;
    float* C    = ws + OFF_C;
    float* MAXV = ws + OFF_MAXV;
    float* W1T  = ws + OFF_W1T;
    float* W2R  = ws + OFF_W2R;
    int*   POS  = (int*)(ws + OFF_POS);
    float* REGN = ws + OFF_REG;
    float* S    = ws + OFF_S;
    float* ACC  = ws + OFF_ACC;

    kt_kernel<<<72, 256, 0, stream>>>(fw, cw, W1T, W2R, MAXV);
    conv1_kernel<<<dim3(4, 256), 256, 0, stream>>>(x1, W1T, fb, X);
    conv2_kernel<<<dim3(4, 127), 256, 0, stream>>>(X, W2R, cb, C, MAXV);
    topk_kernel<<<1, 1024, 0, stream>>>(MAXV, POS);
    gather_kernel<<<128, 64, 0, stream>>>(X, C, POS, REGN, out);
    colsum_kernel<<<1, 576, 0, stream>>>(REGN, shift, S);
    matvec_kernel<<<8, 256, 0, stream>>>(S, lw, lb, ACC);
    finalize_kernel<<<1, 1024, 0, stream>>>(ACC, out);
}